// Round 5
// baseline (73.861 us; speedup 1.0000x reference)
//
#include <hip/hip_runtime.h>

// LearnableHadamard: reference pads x[...,768] to 1024, applies the
// interleaved-butterfly unnormalized FWHT twice, truncates to 768, adds
// residual. The interleaved FWHT is T = P·H (P = bit-reversal permutation,
// H = natural-order Hadamard). P commutes with H and P^2 = I, so
// T^2 = H^2 = N·I = 1024·I. Therefore out = 1024*x + x = 1025*x exactly.
// params' values are unused (only shape[0]=2 matters).
// => single memory-bound elementwise scale; floor = float4-copy ceiling
// (6.29 TB/s measured, ~64 us for 402 MB) + ~3-5 us launch overhead.
//
// R1: 83.3 us @ 4.8 TB/s (1 load + 1 store grid-stride).
// R2: 75.8 us @ 5.3 TB/s (x4 unroll, exact-cover grid).
// R4: 72.4 us @ 5.6 TB/s (x8 unroll + non-temporal load/store).
// R5: x16 unroll — 16 independent nt-loads (256 B/lane in flight) to
//     cover ~900-cyc HBM latency; 3072 blocks (12/CU), exact cover.

typedef float f32x4 __attribute__((ext_vector_type(4)));

__global__ void __launch_bounds__(256)
LearnableHadamard_scale1025(const f32x4* __restrict__ in,
                            f32x4* __restrict__ out) {
    // Each block moves 16 contiguous chunks of 256 float4s (64 KB).
    int base = blockIdx.x * (256 * 16) + threadIdx.x;

    f32x4 v[16];
#pragma unroll
    for (int u = 0; u < 16; ++u)
        v[u] = __builtin_nontemporal_load(&in[base + u * 256]);

#pragma unroll
    for (int u = 0; u < 16; ++u)
        v[u] *= 1025.0f;

#pragma unroll
    for (int u = 0; u < 16; ++u)
        __builtin_nontemporal_store(v[u], &out[base + u * 256]);
}

// Tail-safe fallback for any leftover elements (not used at this shape).
__global__ void LearnableHadamard_scale1025_tail(const float* __restrict__ in,
                                                 float* __restrict__ out,
                                                 int start, int n) {
    int i = start + blockIdx.x * blockDim.x + threadIdx.x;
    if (i < n) out[i] = in[i] * 1025.0f;
}

extern "C" void kernel_launch(void* const* d_in, const int* in_sizes, int n_in,
                              void* d_out, int out_size, void* d_ws, size_t ws_size,
                              hipStream_t stream) {
    const float* x = (const float*)d_in[0];   // (64, 1024, 768) fp32
    float* out = (float*)d_out;

    int n = in_sizes[0];                      // 50,331,648
    int n4 = n >> 2;                          // 12,582,912 float4
    const int per_block = 256 * 16;           // float4s per block
    int grid = n4 / per_block;                // 3072, exact cover

    LearnableHadamard_scale1025<<<grid, 256, 0, stream>>>(
        (const f32x4*)x, (f32x4*)out);

    int covered = grid * per_block * 4;
    if (covered < n) {
        int rem = n - covered;
        LearnableHadamard_scale1025_tail<<<(rem + 255) / 256, 256, 0, stream>>>(
            x, out, covered, n);
    }
}

// Round 6
// 72.508 us; speedup vs baseline: 1.0187x; 1.0187x over previous
//
#include <hip/hip_runtime.h>

// LearnableHadamard: reference pads x[...,768] to 1024, applies the
// interleaved-butterfly unnormalized FWHT twice, truncates to 768, adds
// residual. The interleaved FWHT is T = P·H (P = bit-reversal permutation,
// H = natural-order Hadamard). P commutes with H and P^2 = I, so
// T^2 = H^2 = N·I = 1024·I. Therefore out = 1024*x + x = 1025*x exactly.
// params' values are unused (only shape[0]=2 matters).
// => single memory-bound elementwise scale; floor = float4-copy ceiling
// (6.29 TB/s measured mixed-stream, ~64 us for 402 MB) + launch overhead.
//
// R1: 83.3 us @ 4.8 TB/s (1 load + 1 store grid-stride).
// R2: 75.8 us @ 5.3 TB/s (x4 unroll, exact-cover grid).
// R4: 72.4 us @ 5.6 TB/s (x8 unroll + non-temporal load/store).  << best
// R5: 73.9 us (x16 unroll) — REGRESSED: MLP lever exhausted at x8;
//     limiter is HBM read/write turnaround, not latency coverage.
// R6: restore R4 (best known). This is the practical roofline.

typedef float f32x4 __attribute__((ext_vector_type(4)));

__global__ void __launch_bounds__(256)
LearnableHadamard_scale1025(const f32x4* __restrict__ in,
                            f32x4* __restrict__ out) {
    // Each block moves 8 contiguous chunks of 256 float4s (32 KB).
    int base = blockIdx.x * (256 * 8) + threadIdx.x;

    f32x4 v0 = __builtin_nontemporal_load(&in[base + 0 * 256]);
    f32x4 v1 = __builtin_nontemporal_load(&in[base + 1 * 256]);
    f32x4 v2 = __builtin_nontemporal_load(&in[base + 2 * 256]);
    f32x4 v3 = __builtin_nontemporal_load(&in[base + 3 * 256]);
    f32x4 v4 = __builtin_nontemporal_load(&in[base + 4 * 256]);
    f32x4 v5 = __builtin_nontemporal_load(&in[base + 5 * 256]);
    f32x4 v6 = __builtin_nontemporal_load(&in[base + 6 * 256]);
    f32x4 v7 = __builtin_nontemporal_load(&in[base + 7 * 256]);

    v0 *= 1025.0f;
    v1 *= 1025.0f;
    v2 *= 1025.0f;
    v3 *= 1025.0f;
    v4 *= 1025.0f;
    v5 *= 1025.0f;
    v6 *= 1025.0f;
    v7 *= 1025.0f;

    __builtin_nontemporal_store(v0, &out[base + 0 * 256]);
    __builtin_nontemporal_store(v1, &out[base + 1 * 256]);
    __builtin_nontemporal_store(v2, &out[base + 2 * 256]);
    __builtin_nontemporal_store(v3, &out[base + 3 * 256]);
    __builtin_nontemporal_store(v4, &out[base + 4 * 256]);
    __builtin_nontemporal_store(v5, &out[base + 5 * 256]);
    __builtin_nontemporal_store(v6, &out[base + 6 * 256]);
    __builtin_nontemporal_store(v7, &out[base + 7 * 256]);
}

// Tail-safe fallback for any leftover elements (not used at this shape).
__global__ void LearnableHadamard_scale1025_tail(const float* __restrict__ in,
                                                 float* __restrict__ out,
                                                 int start, int n) {
    int i = start + blockIdx.x * blockDim.x + threadIdx.x;
    if (i < n) out[i] = in[i] * 1025.0f;
}

extern "C" void kernel_launch(void* const* d_in, const int* in_sizes, int n_in,
                              void* d_out, int out_size, void* d_ws, size_t ws_size,
                              hipStream_t stream) {
    const float* x = (const float*)d_in[0];   // (64, 1024, 768) fp32
    float* out = (float*)d_out;

    int n = in_sizes[0];                      // 50,331,648
    int n4 = n >> 2;                          // 12,582,912 float4
    const int per_block = 256 * 8;            // float4s per block
    int grid = n4 / per_block;                // 6144, exact cover

    LearnableHadamard_scale1025<<<grid, 256, 0, stream>>>(
        (const f32x4*)x, (f32x4*)out);

    int covered = grid * per_block * 4;
    if (covered < n) {
        int rem = n - covered;
        LearnableHadamard_scale1025_tail<<<(rem + 255) / 256, 256, 0, stream>>>(
            x, out, covered, n);
    }
}